// Round 13
// baseline (269.565 us; speedup 1.0000x reference)
//
#include <hip/hip_runtime.h>
#include <math.h>

#define N_NODES 50000
#define N_EDGES 800000
#define N_GRAPHS 512
#define IN_DIM 128
#define HID_DIM 256
#define EMB_DIM 128
#define EPS 1e-5f
#define ELLW 64
#define NV4 (N_EDGES / 4)
#define NB 196                      // node buckets: bucket = dst>>8 (256 nodes each)
#define CAP 8192                    // per-bucket edge capacity (mean 4096, +64 sigma)
#define PA_BLOCKS 512
#define CPB ((NV4 + PA_BLOCKS - 1) / PA_BLOCKS)   // int4 chunks per phase-A block (391)
#define F2B_N (N_NODES * IN_DIM / 4)
#define F2B_BLOCKS ((F2B_N + 255) / 256)
#define TW1_BLOCKS ((HID_DIM * IN_DIM + 255) / 256)
#define NSLOTS 128   // partial-stat slots (layer-2 aggw stats)
#define GSLOTS 128   // partial-stat slots (layer-1 stats)
#define AG_BLOCKS ((N_NODES + 63) / 64)   // 782 row panels

typedef __attribute__((ext_vector_type(8))) short bf16x8;
typedef __attribute__((ext_vector_type(4))) float f32x4;
// native vector types for __builtin_nontemporal_* (HIP_vector_type is a class -> rejected)
typedef __attribute__((ext_vector_type(4))) int i32x4;
typedef __attribute__((ext_vector_type(4))) unsigned short u16x4;

static __device__ __forceinline__ unsigned short f2b(float f) {
    unsigned u = __float_as_uint(f);
    return (unsigned short)((u + 0x7fffu + ((u >> 16) & 1u)) >> 16);
}
static __device__ __forceinline__ float dinv_of(int d) {
    return rsqrtf((float)(min(d, ELLW) + 1));
}

// ---------- merged: phase-A edge bucketing (single scan, LDS histogram) + converts ----------
__global__ void __launch_bounds__(256) scatter_convert(const int* __restrict__ src,
                                                       const int* __restrict__ dst,
                                                       int* __restrict__ gcur,
                                                       int* __restrict__ bucketbuf,
                                                       const float* __restrict__ x,
                                                       unsigned short* __restrict__ xbf,
                                                       const float* __restrict__ W1,
                                                       unsigned short* __restrict__ W1t) {
    int b = blockIdx.x;
    if (b < PA_BLOCKS) {
        __shared__ int hcnt[NB], hbase[NB], loff[NB];
        int t = threadIdx.x;
        for (int j = t; j < NB; j += 256) { hcnt[j] = 0; loff[j] = 0; }
        __syncthreads();
        int base = b * CPB;
        int i_end = min(base + CPB, NV4);
        const i32x4* dst4 = (const i32x4*)dst;
        const i32x4* src4 = (const i32x4*)src;
        int i0 = base + t, i1 = base + 256 + t;
        bool val0 = i0 < i_end, val1 = i1 < i_end;
        i32x4 d0 = {0, 0, 0, 0}, s0 = {0, 0, 0, 0};
        i32x4 d1 = {0, 0, 0, 0}, s1 = {0, 0, 0, 0};
        if (val0) {
            d0 = __builtin_nontemporal_load(&dst4[i0]);
            s0 = __builtin_nontemporal_load(&src4[i0]);
        }
        if (val1) {
            d1 = __builtin_nontemporal_load(&dst4[i1]);
            s1 = __builtin_nontemporal_load(&src4[i1]);
        }
        if (val0) {
#pragma unroll
            for (int e = 0; e < 4; ++e) atomicAdd(&hcnt[d0[e] >> 8], 1);
        }
        if (val1) {
#pragma unroll
            for (int e = 0; e < 4; ++e) atomicAdd(&hcnt[d1[e] >> 8], 1);
        }
        __syncthreads();
        for (int j = t; j < NB; j += 256) {
            int c = hcnt[j];
            if (c) hbase[j] = atomicAdd(&gcur[j], c);
        }
        __syncthreads();
        if (val0) {
#pragma unroll
            for (int e = 0; e < 4; ++e) {
                int d = d0[e], bk = d >> 8;
                int o = atomicAdd(&loff[bk], 1);
                int idx = hbase[bk] + o;
                if (idx < CAP) bucketbuf[bk * CAP + idx] = ((d & 255) << 16) | s0[e];
            }
        }
        if (val1) {
#pragma unroll
            for (int e = 0; e < 4; ++e) {
                int d = d1[e], bk = d >> 8;
                int o = atomicAdd(&loff[bk], 1);
                int idx = hbase[bk] + o;
                if (idx < CAP) bucketbuf[bk * CAP + idx] = ((d & 255) << 16) | s1[e];
            }
        }
    } else if (b < PA_BLOCKS + F2B_BLOCKS) {
        int i = (b - PA_BLOCKS) * 256 + threadIdx.x;
        if (i < F2B_N) {
            f32x4 v = __builtin_nontemporal_load(&((const f32x4*)x)[i]);
            u16x4 o;
            o[0] = f2b(v[0]); o[1] = f2b(v[1]); o[2] = f2b(v[2]); o[3] = f2b(v[3]);
            __builtin_nontemporal_store(o, &((u16x4*)xbf)[i]);
        }
    } else {
        int j = (b - PA_BLOCKS - F2B_BLOCKS) * 256 + threadIdx.x;
        if (j < HID_DIM * IN_DIM) {
            int n = j >> 7;
            int k = j & 127;
            W1t[j] = f2b(W1[k * HID_DIM + n]);
        }
    }
}

// ---------- phase B: per-bucket ELL build, all position atomics in LDS ----------
__global__ void __launch_bounds__(256) build_ell(const int* __restrict__ gcur,
                                                 const int* __restrict__ bucketbuf,
                                                 int* __restrict__ fill,
                                                 int* __restrict__ col) {
    __shared__ unsigned short lcol[256 * ELLW];   // 32 KB
    __shared__ int lfill[256];
    int b = blockIdx.x;
    int t = threadIdx.x;
    lfill[t] = 0;
    __syncthreads();
    int n = min(gcur[b], CAP);
    const int* buf = bucketbuf + b * CAP;
    for (int i = t; i < n; i += 256) {
        int p = buf[i];
        int dl = p >> 16;                 // local node (0..255); sign bit clear
        int pos = atomicAdd(&lfill[dl], 1);
        if (pos < ELLW) lcol[(dl << 6) + pos] = (unsigned short)(p & 0xFFFF);
    }
    __syncthreads();
    int v = (b << 8) + t;
    if (v < N_NODES) fill[v] = lfill[t];
    for (int idx4 = t; idx4 < 256 * (ELLW / 4); idx4 += 256) {
        int row = idx4 >> 4;
        int vv = (b << 8) + row;
        if (vv < N_NODES) {
            int c0 = (idx4 & 15) << 2;
            u16x4 w = *(const u16x4*)&lcol[(row << 6) + c0];
            int4 o4 = make_int4(w[0], w[1], w[2], w[3]);
            *(int4*)&col[((size_t)vv << 6) + c0] = o4;
        }
    }
}

// ---------- helper: 8-channel bf16 accumulate ----------
static __device__ __forceinline__ void acc8(float* acc, uint4 r, float w) {
    const unsigned* u = (const unsigned*)&r;
#pragma unroll
    for (int k = 0; k < 4; ++k) {
        float lo = __uint_as_float((u[k] & 0xFFFFu) << 16);
        float hi = __uint_as_float(u[k] & 0xFFFF0000u);
        acc[2 * k]     += w * lo;
        acc[2 * k + 1] += w * hi;
    }
}

// ---------- fused layer-1 (512 threads): agg -> LDS A-tile -> 8-wave MFMA -> y1+stats ----------
// r12's 256-thread fusion was occupancy-starved (25%, 12 waves/CU — gather latency
// exposed). 512 threads/block doubles resident waves (24/CU): phase 1 = 32 groups x
// 2 nodes; phase 2 = 8 waves tiling 64x256 directly (wave (w&1,w>>1) owns 32x64),
// barrier-free K-loop, stats via shfl + direct slotted atomics (no LDS reduce).
__global__ void __launch_bounds__(512) fused_aggemm1(const unsigned short* __restrict__ xbf,
                                                     const int* __restrict__ deg,
                                                     const int* __restrict__ col,
                                                     const unsigned short* __restrict__ W1t,
                                                     const float* __restrict__ bias,
                                                     unsigned short* __restrict__ y1,
                                                     float* __restrict__ sums,
                                                     float* __restrict__ sumsqs) {
    const int LDA = 136;                      // 128 + 8 pad shorts; 272B rows (16B-aligned)
    __shared__ unsigned short As[64 * LDA];   // 17.4 KB
    int tid = threadIdx.x;
    int lane = tid & 63;
    int w = tid >> 6;                         // 0..7
    int p = lane & 15;
    int grp = tid >> 4;                       // 0..31
    int bm = blockIdx.x * 64;
    int sl = (lane >> 4) << 4;

    // ---- phase 1: each 16-lane group aggregates 2 nodes ----
#pragma unroll
    for (int it = 0; it < 2; ++it) {
        int vl = grp + (it << 5);             // 0..63
        int v = bm + vl;
        float o[8] = {};
        if (v < N_NODES) {
            int dcl = min(deg[v], ELLW);
            uint4 selfr = *(const uint4*)(xbf + (size_t)v * 128 + p * 8);
            float acc[8] = {};
            for (int sel = 0; sel < 4; ++sel) {
                int base = sel * 16;
                if (base >= dcl) break;
                int idx = base + p;
                int cidx = min(idx, dcl - 1);
                int u_l = col[((size_t)v << 6) + cidx];
                float w_l = (idx < dcl) ? dinv_of(deg[u_l]) : 0.f;
                int n = min(16, dcl - base);
                for (int e0 = 0; e0 < n; e0 += 4) {
                    int u0 = __shfl(u_l, sl + e0, 64);
                    int u1 = __shfl(u_l, sl + e0 + 1, 64);
                    int u2 = __shfl(u_l, sl + e0 + 2, 64);
                    int u3 = __shfl(u_l, sl + e0 + 3, 64);
                    float w0 = __shfl(w_l, sl + e0, 64);
                    float w1 = __shfl(w_l, sl + e0 + 1, 64);
                    float w2 = __shfl(w_l, sl + e0 + 2, 64);
                    float w3 = __shfl(w_l, sl + e0 + 3, 64);
                    uint4 d0 = *(const uint4*)(xbf + (size_t)u0 * 128 + p * 8);
                    uint4 d1 = *(const uint4*)(xbf + (size_t)u1 * 128 + p * 8);
                    uint4 d2 = *(const uint4*)(xbf + (size_t)u2 * 128 + p * 8);
                    uint4 d3 = *(const uint4*)(xbf + (size_t)u3 * 128 + p * 8);
                    acc8(acc, d0, w0);
                    acc8(acc, d1, w1);
                    acc8(acc, d2, w2);
                    acc8(acc, d3, w3);
                }
            }
            const unsigned* su = (const unsigned*)&selfr;
            float dv = rsqrtf((float)(dcl + 1));
            float dv2 = dv * dv;
#pragma unroll
            for (int k = 0; k < 4; ++k) {
                float lo = __uint_as_float((su[k] & 0xFFFFu) << 16);
                float hi = __uint_as_float(su[k] & 0xFFFF0000u);
                o[2 * k]     = dv * acc[2 * k]     + lo * dv2;
                o[2 * k + 1] = dv * acc[2 * k + 1] + hi * dv2;
            }
        }
        uint4 packed;
        unsigned* pu = (unsigned*)&packed;
#pragma unroll
        for (int k = 0; k < 4; ++k)
            pu[k] = (unsigned)f2b(o[2 * k]) | ((unsigned)f2b(o[2 * k + 1]) << 16);
        *(uint4*)&As[vl * LDA + p * 8] = packed;
    }
    __syncthreads();

    // ---- phase 2: 8 waves tile 64x256; A from LDS, B (W1t, L2-hot) from global ----
    int wr = (w & 1) * 32;
    int wcg = (w >> 1) * 64;
    int l15 = lane & 15, q = lane >> 4;
    f32x4 acc2[2][4] = {};
#pragma unroll
    for (int k0 = 0; k0 < 128; k0 += 32) {
        bf16x8 a0 = *(const bf16x8*)&As[(wr + 0 + l15) * LDA + k0 + q * 8];
        bf16x8 a1 = *(const bf16x8*)&As[(wr + 16 + l15) * LDA + k0 + q * 8];
#pragma unroll
        for (int ni = 0; ni < 4; ++ni) {
            bf16x8 b = *(const bf16x8*)(W1t + (size_t)(wcg + ni * 16 + l15) * 128 + k0 + q * 8);
            acc2[0][ni] = __builtin_amdgcn_mfma_f32_16x16x32_bf16(a0, b, acc2[0][ni], 0, 0, 0);
            acc2[1][ni] = __builtin_amdgcn_mfma_f32_16x16x32_bf16(a1, b, acc2[1][ni], 0, 0, 0);
        }
    }
    int slot = blockIdx.x & (GSLOTS - 1);
#pragma unroll
    for (int ni = 0; ni < 4; ++ni) {
        int colc = wcg + ni * 16 + l15;
        float bv = bias[colc];
        float scol = 0.f, qcol = 0.f;
#pragma unroll
        for (int mi = 0; mi < 2; ++mi) {
#pragma unroll
            for (int r = 0; r < 4; ++r) {
                int row = bm + wr + mi * 16 + q * 4 + r;
                if (row < N_NODES) {
                    float vv = acc2[mi][ni][r] + bv;
                    vv = fmaxf(vv, 0.f);   // layer-1 relu
                    y1[(size_t)row * HID_DIM + colc] = f2b(vv);
                    scol += vv; qcol += vv * vv;
                }
            }
        }
        scol += __shfl_xor(scol, 16, 64);
        scol += __shfl_xor(scol, 32, 64);
        qcol += __shfl_xor(qcol, 16, 64);
        qcol += __shfl_xor(qcol, 32, 64);
        if (lane < 16) {
            atomicAdd(&sums[slot * HID_DIM + colc], scol);
            atomicAdd(&sumsqs[slot * HID_DIM + colc], qcol);
        }
    }
}

// ---------- quarter-wave-per-node ELL aggregation (layer 2) ----------
template <bool RELU, bool OUT_BF, bool BIAS, bool STATS>
__global__ void __launch_bounds__(256) aggw_kernel(const unsigned short* __restrict__ h,
                                                   const int* __restrict__ deg,
                                                   const int* __restrict__ col,
                                                   const float* __restrict__ bias,
                                                   void* __restrict__ y,
                                                   float* __restrict__ sumP,
                                                   float* __restrict__ sqP) {
    __shared__ float sv[STATS ? 16 : 1][STATS ? 128 : 1];
    int tid = threadIdx.x;
    int lane = tid & 63;
    int grpw = lane >> 4;                 // group within wave (0..3)
    int p = lane & 15;
    int grp = tid >> 4;                   // group within block (0..15)
    int v = blockIdx.x * 16 + grp;

    int dcl = min(deg[v], ELLW);
    uint4 selfr = *(const uint4*)(h + (size_t)v * 128 + p * 8);

    float acc[8] = {};
    int sl = grpw << 4;
#pragma unroll 4
    for (int sel = 0; sel < 4; ++sel) {
        int base = sel * 16;
        if (base >= dcl) break;
        int idx = base + p;
        int cidx = min(idx, dcl - 1);
        int u_l = col[(v << 6) + cidx];
        float w_l = (idx < dcl) ? dinv_of(deg[u_l]) : 0.f;
        int n = min(16, dcl - base);
        for (int e0 = 0; e0 < n; e0 += 4) {
            int u0 = __shfl(u_l, sl + e0, 64);
            int u1 = __shfl(u_l, sl + e0 + 1, 64);
            int u2 = __shfl(u_l, sl + e0 + 2, 64);
            int u3 = __shfl(u_l, sl + e0 + 3, 64);
            float w0 = __shfl(w_l, sl + e0, 64);
            float w1 = __shfl(w_l, sl + e0 + 1, 64);
            float w2 = __shfl(w_l, sl + e0 + 2, 64);
            float w3 = __shfl(w_l, sl + e0 + 3, 64);
            uint4 d0 = *(const uint4*)(h + (size_t)u0 * 128 + p * 8);
            uint4 d1 = *(const uint4*)(h + (size_t)u1 * 128 + p * 8);
            uint4 d2 = *(const uint4*)(h + (size_t)u2 * 128 + p * 8);
            uint4 d3 = *(const uint4*)(h + (size_t)u3 * 128 + p * 8);
            acc8(acc, d0, w0);
            acc8(acc, d1, w1);
            acc8(acc, d2, w2);
            acc8(acc, d3, w3);
        }
    }

    // epilogue: all 16 lanes of the group finalize their node's 8 channels
    {
        const unsigned* su = (const unsigned*)&selfr;
        float dv = rsqrtf((float)(dcl + 1));
        float dv2 = dv * dv;
        float o[8];
#pragma unroll
        for (int k = 0; k < 4; ++k) {
            float lo = __uint_as_float((su[k] & 0xFFFFu) << 16);
            float hi = __uint_as_float(su[k] & 0xFFFF0000u);
            o[2 * k]     = dv * acc[2 * k]     + lo * dv2;
            o[2 * k + 1] = dv * acc[2 * k + 1] + hi * dv2;
        }
        if (BIAS) {
            float4 bv0 = *(const float4*)&bias[p * 8];
            float4 bv1 = *(const float4*)&bias[p * 8 + 4];
            o[0] += bv0.x; o[1] += bv0.y; o[2] += bv0.z; o[3] += bv0.w;
            o[4] += bv1.x; o[5] += bv1.y; o[6] += bv1.z; o[7] += bv1.w;
        }
        if (RELU) {
#pragma unroll
            for (int k = 0; k < 8; ++k) o[k] = fmaxf(o[k], 0.f);
        }
        if (OUT_BF) {
            uint4 packed;
            unsigned* pu = (unsigned*)&packed;
#pragma unroll
            for (int k = 0; k < 4; ++k)
                pu[k] = (unsigned)f2b(o[2 * k]) | ((unsigned)f2b(o[2 * k + 1]) << 16);
            *(uint4*)((unsigned short*)y + (size_t)v * 128 + p * 8) = packed;
        } else {
            float* yf = (float*)y + (size_t)v * 128 + p * 8;
            *(float4*)yf = make_float4(o[0], o[1], o[2], o[3]);
            *(float4*)(yf + 4) = make_float4(o[4], o[5], o[6], o[7]);
        }
        if (STATS) {
#pragma unroll
            for (int k = 0; k < 8; ++k) sv[grp][p * 8 + k] = o[k];
        }
    }

    if (STATS) {
        __syncthreads();   // uniform: STATS is compile-time
        if (tid < 128) {
            float s = 0.f, q = 0.f;
#pragma unroll
            for (int r = 0; r < 16; ++r) {
                float val = sv[r][tid];
                s += val;
                q += val * val;
            }
            int slot = blockIdx.x & (NSLOTS - 1);
            atomicAdd(&sumP[slot * 128 + tid], s);
            atomicAdd(&sqP[slot * 128 + tid], q);
        }
    }
}

// ---------- MFMA bf16 GEMM (64x64, LDT=40), register-prefetched K loop (layer 2) ----------
template <bool RELU, bool STATS>
__global__ void __launch_bounds__(256) mfma_gemm_kernel(const unsigned short* __restrict__ A,
                                                        const unsigned short* __restrict__ Bt,
                                                        const float* __restrict__ bias,
                                                        unsigned short* __restrict__ C,
                                                        float* __restrict__ sums,
                                                        float* __restrict__ sumsqs,
                                                        int M, int N, int K) {
    const int LDT = 40;  // 32 + 8 pad (ushorts)
    __shared__ unsigned short As[64 * LDT];
    __shared__ unsigned short Bs[64 * LDT];
    int tid = threadIdx.x;
    int bm = blockIdx.x * 64;
    int bn = blockIdx.y * 64;
    int lr = tid >> 2;
    int lc = (tid & 3) * 8;
    int lane = tid & 63;
    int w = tid >> 6;
    int wr = (w >> 1) * 32, wc = (w & 1) * 32;
    int l15 = lane & 15, q = lane >> 4;

    f32x4 acc[2][2] = {};
    bool arow_ok = (bm + lr) < M;
    const unsigned short* Aptr = A + (size_t)(bm + lr) * K + lc;
    const unsigned short* Bptr = Bt + (size_t)(bn + lr) * K + lc;

    uint4 av = arow_ok ? *(const uint4*)(Aptr) : make_uint4(0u, 0u, 0u, 0u);
    uint4 bv = *(const uint4*)(Bptr);

    for (int k0 = 0; k0 < K; k0 += 32) {
        *(uint4*)&As[lr * LDT + lc] = av;
        *(uint4*)&Bs[lr * LDT + lc] = bv;
        __syncthreads();
        if (k0 + 32 < K) {   // prefetch next tile; latency hides under ds_read+MFMA
            av = arow_ok ? *(const uint4*)(Aptr + k0 + 32) : make_uint4(0u, 0u, 0u, 0u);
            bv = *(const uint4*)(Bptr + k0 + 32);
        }
        bf16x8 a0 = *(const bf16x8*)&As[(wr + 0 + l15) * LDT + q * 8];
        bf16x8 a1 = *(const bf16x8*)&As[(wr + 16 + l15) * LDT + q * 8];
        bf16x8 b0 = *(const bf16x8*)&Bs[(wc + 0 + l15) * LDT + q * 8];
        bf16x8 b1 = *(const bf16x8*)&Bs[(wc + 16 + l15) * LDT + q * 8];
        acc[0][0] = __builtin_amdgcn_mfma_f32_16x16x32_bf16(a0, b0, acc[0][0], 0, 0, 0);
        acc[0][1] = __builtin_amdgcn_mfma_f32_16x16x32_bf16(a0, b1, acc[0][1], 0, 0, 0);
        acc[1][0] = __builtin_amdgcn_mfma_f32_16x16x32_bf16(a1, b0, acc[1][0], 0, 0, 0);
        acc[1][1] = __builtin_amdgcn_mfma_f32_16x16x32_bf16(a1, b1, acc[1][1], 0, 0, 0);
        __syncthreads();
    }

#pragma unroll
    for (int mi = 0; mi < 2; ++mi)
#pragma unroll
        for (int ni = 0; ni < 2; ++ni) {
            int colc = bn + wc + ni * 16 + l15;
            float bv2 = bias ? bias[colc] : 0.f;
#pragma unroll
            for (int r = 0; r < 4; ++r) {
                int row = bm + wr + mi * 16 + q * 4 + r;
                if (row < M) {
                    float vv = acc[mi][ni][r] + bv2;
                    if (RELU) vv = fmaxf(vv, 0.f);
                    C[(size_t)row * N + colc] = f2b(vv);
                }
            }
        }
}

// ---------- fold BN1 into W2 (8 blocks); reduces GSLOTS stat partials first ----------
__global__ void __launch_bounds__(256) prep2_kernel(const float* __restrict__ sum1P,
                                                    const float* __restrict__ sumsq1P,
                                                    const float* __restrict__ gamma1,
                                                    const float* __restrict__ beta1,
                                                    const float* __restrict__ W2,
                                                    unsigned short* __restrict__ W2pt,
                                                    float* __restrict__ bc2) {
    __shared__ float a1s[HID_DIM], s1s[HID_DIM];
    __shared__ float bp[16][17];
    int t = threadIdx.x;
    {
        float s = 0.f, q = 0.f;
#pragma unroll 8
        for (int j = 0; j < GSLOTS; ++j) {
            s += sum1P[j * HID_DIM + t];
            q += sumsq1P[j * HID_DIM + t];
        }
        float m = s * (1.f / N_NODES);
        float var = q * (1.f / N_NODES) - m * m;
        float a = gamma1[t] * rsqrtf(var + EPS);
        a1s[t] = a;
        s1s[t] = beta1[t] - m * a;
    }
    __syncthreads();
    int row = blockIdx.x * 16 + (t & 15);
    int ks = t >> 4;
    float bacc = 0.f;
    unsigned short wloc[16];
#pragma unroll
    for (int j = 0; j < 16; ++j) {
        int k = ks * 16 + j;
        float wv = W2[k * EMB_DIM + row];
        wloc[j] = f2b(a1s[k] * wv);
        bacc += s1s[k] * wv;
    }
    *(uint4*)&W2pt[(size_t)row * HID_DIM + ks * 16]     = *(uint4*)&wloc[0];
    *(uint4*)&W2pt[(size_t)row * HID_DIM + ks * 16 + 8] = *(uint4*)&wloc[8];
    bp[t & 15][ks] = bacc;
    __syncthreads();
    if (t < 16) {
        float s = 0.f;
#pragma unroll
        for (int g = 0; g < 16; ++g) s += bp[t][g];
        bc2[blockIdx.x * 16 + t] = s;
    }
}

// ---------- segmented max per graph; finalizes layer-2 partial stats in-block ----------
__global__ void __launch_bounds__(128) segmax_kernel(const float* __restrict__ y,
                                                     const float* __restrict__ sumP,
                                                     const float* __restrict__ sqP,
                                                     const float* __restrict__ gamma2,
                                                     const float* __restrict__ beta2,
                                                     const int* __restrict__ batch,
                                                     float* __restrict__ out) {
    __shared__ int sh[2];
    int g = blockIdx.x;
    int c = threadIdx.x;
    float s2 = 0.f, q2 = 0.f;
#pragma unroll 8
    for (int j = 0; j < NSLOTS; ++j) {
        s2 += sumP[j * 128 + c];
        q2 += sqP[j * 128 + c];
    }
    float mch = s2 * (1.f / N_NODES);
    float var = q2 * (1.f / N_NODES) - mch * mch;
    float ac = gamma2[c] * rsqrtf(var + EPS);
    float sc = beta2[c] - mch * ac;
    if (threadIdx.x == 0) {
        int lo = 0, hi = N_NODES;
        while (lo < hi) { int mid = (lo + hi) >> 1; if (batch[mid] < g) lo = mid + 1; else hi = mid; }
        sh[0] = lo;
        hi = N_NODES;
        while (lo < hi) { int mid = (lo + hi) >> 1; if (batch[mid] < g + 1) lo = mid + 1; else hi = mid; }
        sh[1] = lo;
    }
    __syncthreads();
    int beg = sh[0], end = sh[1];
    float m = -INFINITY;
    for (int v = beg; v < end; ++v) {
        m = fmaxf(m, fmaf(ac, y[(size_t)v * EMB_DIM + c], sc));
    }
    out[(size_t)g * EMB_DIM + c] = m;
}

extern "C" void kernel_launch(void* const* d_in, const int* in_sizes, int n_in,
                              void* d_out, int out_size, void* d_ws, size_t ws_size,
                              hipStream_t stream) {
    const float* x      = (const float*)d_in[0];
    const int*   ei     = (const int*)d_in[1];
    const int*   batch  = (const int*)d_in[2];
    const float* W1     = (const float*)d_in[3];
    const float* b1     = (const float*)d_in[4];
    const float* gamma1 = (const float*)d_in[5];
    const float* beta1  = (const float*)d_in[6];
    const float* W2     = (const float*)d_in[7];
    const float* b2     = (const float*)d_in[8];
    const float* gamma2 = (const float*)d_in[9];
    const float* beta2  = (const float*)d_in[10];
    float* out = (float*)d_out;

    char* ws = (char*)d_ws;
    size_t off = 0;
    auto alloc = [&](size_t bytes) -> char* {
        char* p = ws + off;
        off = (off + bytes + 255) & ~(size_t)255;
        return p;
    };
    int*   gcur    = (int*)alloc((size_t)NB * 4);                  // bucket cursors
    float* gsumP   = (float*)alloc((size_t)GSLOTS * HID_DIM * 4);  // layer-1 stat partials
    float* gsqP    = (float*)alloc((size_t)GSLOTS * HID_DIM * 4);
    float* sumP    = (float*)alloc((size_t)NSLOTS * 128 * 4);      // layer-2 stat partials
    float* sqP     = (float*)alloc((size_t)NSLOTS * 128 * 4);
    size_t zbytes = off;
    int*   fill   = (int*)alloc((size_t)N_NODES * 4);              // fully overwritten by build_ell
    int*   bucketbuf = (int*)alloc((size_t)NB * CAP * 4);
    int*   col    = (int*)alloc((size_t)N_NODES * ELLW * 4);
    float* bc2    = (float*)alloc((size_t)EMB_DIM * 4);
    unsigned short* W1t  = (unsigned short*)alloc((size_t)HID_DIM * IN_DIM * 2);
    unsigned short* W2pt = (unsigned short*)alloc((size_t)HID_DIM * EMB_DIM * 2);
    unsigned short* xbf  = (unsigned short*)alloc((size_t)N_NODES * IN_DIM * 2);   // also y2 region
    unsigned short* y1bf = (unsigned short*)alloc((size_t)N_NODES * HID_DIM * 2);
    unsigned short* gbf  = (unsigned short*)alloc((size_t)N_NODES * EMB_DIM * 2);
    float* y2 = (float*)xbf;  // xbf dead after layer-2 GEMM input is gbf; 25.6 MB region
    (void)ws_size; (void)in_sizes; (void)n_in; (void)out_size;

    const int* src  = ei;
    const int* dstp = ei + N_EDGES;

    hipMemsetAsync(ws, 0, zbytes, stream);   // zero gcur + all stat partials in one call

    // merged: phase-A bucketing (single scan) + x->bf16 + W1 transpose
    scatter_convert<<<PA_BLOCKS + F2B_BLOCKS + TW1_BLOCKS, 256, 0, stream>>>(
        src, dstp, gcur, bucketbuf, x, xbf, W1, W1t);
    // phase B: per-bucket ELL build via LDS atomics, coalesced flush
    build_ell<<<NB, 256, 0, stream>>>(gcur, bucketbuf, fill, col);

    // Layer 1 fused (512 threads): y1 = relu((A xbf) @ W1 + b1), stats
    fused_aggemm1<<<AG_BLOCKS, 512, 0, stream>>>(xbf, fill, col, W1t, b1, y1bf,
                                                 gsumP, gsqP);

    // Fold BN1 into W2 (transposed bf16) + pre-aggregation column bias bc2
    prep2_kernel<<<8, 256, 0, stream>>>(gsumP, gsqP, gamma1, beta1, W2, W2pt, bc2);

    // Layer 2: g = y1@W2p + bc2 (bf16), y2 = relu(A g + b2) (fp32) with slotted stats
    dim3 g2((N_NODES + 63) / 64, EMB_DIM / 64);
    mfma_gemm_kernel<false, false><<<g2, 256, 0, stream>>>(y1bf, W2pt, bc2, gbf,
                                                           nullptr, nullptr,
                                                           N_NODES, EMB_DIM, HID_DIM);
    aggw_kernel<true, false, true, true><<<N_NODES / 16, 256, 0, stream>>>(
        gbf, fill, col, b2, y2, sumP, sqP);

    // fused BN2-finalize (reduce NSLOTS partials) + per-graph segmented max
    segmax_kernel<<<N_GRAPHS, 128, 0, stream>>>(y2, sumP, sqP,
                                                gamma2, beta2, batch, out);
}

// Round 15
// 258.328 us; speedup vs baseline: 1.0435x; 1.0435x over previous
//
#include <hip/hip_runtime.h>
#include <math.h>

#define N_NODES 50000
#define N_EDGES 800000
#define N_GRAPHS 512
#define IN_DIM 128
#define HID_DIM 256
#define EMB_DIM 128
#define EPS 1e-5f
#define ELLW 64
#define NV4 (N_EDGES / 4)
#define NB 196                      // node buckets: bucket = dst>>8 (256 nodes each)
#define CAP 8192                    // per-bucket edge capacity (mean 4096, +64 sigma)
#define PA_BLOCKS 512
#define CPB ((NV4 + PA_BLOCKS - 1) / PA_BLOCKS)   // int4 chunks per phase-A block (391)
#define F2B_N (N_NODES * IN_DIM / 4)
#define F2B_BLOCKS ((F2B_N + 255) / 256)
#define TW1_BLOCKS ((HID_DIM * IN_DIM + 255) / 256)
#define NSLOTS 128   // partial-stat slots (layer-2 aggw stats)
#define GSLOTS 128   // partial-stat slots (layer-1 gemm stats)

typedef __attribute__((ext_vector_type(8))) short bf16x8;
typedef __attribute__((ext_vector_type(4))) float f32x4;
// native vector types for __builtin_nontemporal_* (HIP_vector_type is a class -> rejected)
typedef __attribute__((ext_vector_type(4))) int i32x4;
typedef __attribute__((ext_vector_type(4))) unsigned short u16x4;

static __device__ __forceinline__ unsigned short f2b(float f) {
    unsigned u = __float_as_uint(f);
    return (unsigned short)((u + 0x7fffu + ((u >> 16) & 1u)) >> 16);
}
static __device__ __forceinline__ float dinv_of(int d) {
    return rsqrtf((float)(min(d, ELLW) + 1));
}

// ---------- merged: phase-A edge bucketing (single scan, LDS histogram) + converts ----------
__global__ void __launch_bounds__(256) scatter_convert(const int* __restrict__ src,
                                                       const int* __restrict__ dst,
                                                       int* __restrict__ gcur,
                                                       int* __restrict__ bucketbuf,
                                                       const float* __restrict__ x,
                                                       unsigned short* __restrict__ xbf,
                                                       const float* __restrict__ W1,
                                                       unsigned short* __restrict__ W1t) {
    int b = blockIdx.x;
    if (b < PA_BLOCKS) {
        __shared__ int hcnt[NB], hbase[NB], loff[NB];
        int t = threadIdx.x;
        for (int j = t; j < NB; j += 256) { hcnt[j] = 0; loff[j] = 0; }
        __syncthreads();
        int base = b * CPB;
        int i_end = min(base + CPB, NV4);
        const i32x4* dst4 = (const i32x4*)dst;
        const i32x4* src4 = (const i32x4*)src;
        int i0 = base + t, i1 = base + 256 + t;
        bool val0 = i0 < i_end, val1 = i1 < i_end;
        i32x4 d0 = {0, 0, 0, 0}, s0 = {0, 0, 0, 0};
        i32x4 d1 = {0, 0, 0, 0}, s1 = {0, 0, 0, 0};
        if (val0) {
            d0 = __builtin_nontemporal_load(&dst4[i0]);
            s0 = __builtin_nontemporal_load(&src4[i0]);
        }
        if (val1) {
            d1 = __builtin_nontemporal_load(&dst4[i1]);
            s1 = __builtin_nontemporal_load(&src4[i1]);
        }
        if (val0) {
#pragma unroll
            for (int e = 0; e < 4; ++e) atomicAdd(&hcnt[d0[e] >> 8], 1);
        }
        if (val1) {
#pragma unroll
            for (int e = 0; e < 4; ++e) atomicAdd(&hcnt[d1[e] >> 8], 1);
        }
        __syncthreads();
        for (int j = t; j < NB; j += 256) {
            int c = hcnt[j];
            if (c) hbase[j] = atomicAdd(&gcur[j], c);
        }
        __syncthreads();
        if (val0) {
#pragma unroll
            for (int e = 0; e < 4; ++e) {
                int d = d0[e], bk = d >> 8;
                int o = atomicAdd(&loff[bk], 1);
                int idx = hbase[bk] + o;
                if (idx < CAP) bucketbuf[bk * CAP + idx] = ((d & 255) << 16) | s0[e];
            }
        }
        if (val1) {
#pragma unroll
            for (int e = 0; e < 4; ++e) {
                int d = d1[e], bk = d >> 8;
                int o = atomicAdd(&loff[bk], 1);
                int idx = hbase[bk] + o;
                if (idx < CAP) bucketbuf[bk * CAP + idx] = ((d & 255) << 16) | s1[e];
            }
        }
    } else if (b < PA_BLOCKS + F2B_BLOCKS) {
        int i = (b - PA_BLOCKS) * 256 + threadIdx.x;
        if (i < F2B_N) {
            f32x4 v = __builtin_nontemporal_load(&((const f32x4*)x)[i]);
            u16x4 o;
            o[0] = f2b(v[0]); o[1] = f2b(v[1]); o[2] = f2b(v[2]); o[3] = f2b(v[3]);
            __builtin_nontemporal_store(o, &((u16x4*)xbf)[i]);
        }
    } else {
        int j = (b - PA_BLOCKS - F2B_BLOCKS) * 256 + threadIdx.x;
        if (j < HID_DIM * IN_DIM) {
            int n = j >> 7;
            int k = j & 127;
            W1t[j] = f2b(W1[k * HID_DIM + n]);
        }
    }
}

// ---------- phase B: per-bucket ELL build, all position atomics in LDS ----------
__global__ void __launch_bounds__(256) build_ell(const int* __restrict__ gcur,
                                                 const int* __restrict__ bucketbuf,
                                                 int* __restrict__ fill,
                                                 int* __restrict__ col) {
    __shared__ unsigned short lcol[256 * ELLW];   // 32 KB
    __shared__ int lfill[256];
    int b = blockIdx.x;
    int t = threadIdx.x;
    lfill[t] = 0;
    __syncthreads();
    int n = min(gcur[b], CAP);
    const int* buf = bucketbuf + b * CAP;
    for (int i = t; i < n; i += 256) {
        int p = buf[i];
        int dl = p >> 16;                 // local node (0..255); sign bit clear
        int pos = atomicAdd(&lfill[dl], 1);
        if (pos < ELLW) lcol[(dl << 6) + pos] = (unsigned short)(p & 0xFFFF);
    }
    __syncthreads();
    int v = (b << 8) + t;
    if (v < N_NODES) fill[v] = lfill[t];
    for (int idx4 = t; idx4 < 256 * (ELLW / 4); idx4 += 256) {
        int row = idx4 >> 4;
        int vv = (b << 8) + row;
        if (vv < N_NODES) {
            int c0 = (idx4 & 15) << 2;
            u16x4 w = *(const u16x4*)&lcol[(row << 6) + c0];
            int4 o4 = make_int4(w[0], w[1], w[2], w[3]);
            *(int4*)&col[((size_t)vv << 6) + c0] = o4;
        }
    }
}

// ---------- quarter-wave-per-node ELL aggregation ----------
static __device__ __forceinline__ void acc8(float* acc, uint4 r, float w) {
    const unsigned* u = (const unsigned*)&r;
#pragma unroll
    for (int k = 0; k < 4; ++k) {
        float lo = __uint_as_float((u[k] & 0xFFFFu) << 16);
        float hi = __uint_as_float(u[k] & 0xFFFF0000u);
        acc[2 * k]     += w * lo;
        acc[2 * k + 1] += w * hi;
    }
}

template <bool RELU, bool OUT_BF, bool BIAS, bool STATS>
__global__ void __launch_bounds__(256) aggw_kernel(const unsigned short* __restrict__ h,
                                                   const int* __restrict__ deg,
                                                   const int* __restrict__ col,
                                                   const float* __restrict__ bias,
                                                   void* __restrict__ y,
                                                   float* __restrict__ sumP,
                                                   float* __restrict__ sqP) {
    __shared__ float sv[STATS ? 16 : 1][STATS ? 128 : 1];
    int tid = threadIdx.x;
    int lane = tid & 63;
    int grpw = lane >> 4;                 // group within wave (0..3)
    int p = lane & 15;
    int grp = tid >> 4;                   // group within block (0..15)
    int v = blockIdx.x * 16 + grp;

    int dcl = min(deg[v], ELLW);
    uint4 selfr = *(const uint4*)(h + (size_t)v * 128 + p * 8);

    float acc[8] = {};
    int sl = grpw << 4;
#pragma unroll 4
    for (int sel = 0; sel < 4; ++sel) {
        int base = sel * 16;
        if (base >= dcl) break;
        int idx = base + p;
        int cidx = min(idx, dcl - 1);
        int u_l = col[(v << 6) + cidx];
        float w_l = (idx < dcl) ? dinv_of(deg[u_l]) : 0.f;
        int n = min(16, dcl - base);
        for (int e0 = 0; e0 < n; e0 += 4) {
            int u0 = __shfl(u_l, sl + e0, 64);
            int u1 = __shfl(u_l, sl + e0 + 1, 64);
            int u2 = __shfl(u_l, sl + e0 + 2, 64);
            int u3 = __shfl(u_l, sl + e0 + 3, 64);
            float w0 = __shfl(w_l, sl + e0, 64);
            float w1 = __shfl(w_l, sl + e0 + 1, 64);
            float w2 = __shfl(w_l, sl + e0 + 2, 64);
            float w3 = __shfl(w_l, sl + e0 + 3, 64);
            uint4 d0 = *(const uint4*)(h + (size_t)u0 * 128 + p * 8);
            uint4 d1 = *(const uint4*)(h + (size_t)u1 * 128 + p * 8);
            uint4 d2 = *(const uint4*)(h + (size_t)u2 * 128 + p * 8);
            uint4 d3 = *(const uint4*)(h + (size_t)u3 * 128 + p * 8);
            acc8(acc, d0, w0);
            acc8(acc, d1, w1);
            acc8(acc, d2, w2);
            acc8(acc, d3, w3);
        }
    }

    // epilogue: all 16 lanes of the group finalize their node's 8 channels
    {
        const unsigned* su = (const unsigned*)&selfr;
        float dv = rsqrtf((float)(dcl + 1));
        float dv2 = dv * dv;
        float o[8];
#pragma unroll
        for (int k = 0; k < 4; ++k) {
            float lo = __uint_as_float((su[k] & 0xFFFFu) << 16);
            float hi = __uint_as_float(su[k] & 0xFFFF0000u);
            o[2 * k]     = dv * acc[2 * k]     + lo * dv2;
            o[2 * k + 1] = dv * acc[2 * k + 1] + hi * dv2;
        }
        if (BIAS) {
            float4 bv0 = *(const float4*)&bias[p * 8];
            float4 bv1 = *(const float4*)&bias[p * 8 + 4];
            o[0] += bv0.x; o[1] += bv0.y; o[2] += bv0.z; o[3] += bv0.w;
            o[4] += bv1.x; o[5] += bv1.y; o[6] += bv1.z; o[7] += bv1.w;
        }
        if (RELU) {
#pragma unroll
            for (int k = 0; k < 8; ++k) o[k] = fmaxf(o[k], 0.f);
        }
        if (OUT_BF) {
            uint4 packed;
            unsigned* pu = (unsigned*)&packed;
#pragma unroll
            for (int k = 0; k < 4; ++k)
                pu[k] = (unsigned)f2b(o[2 * k]) | ((unsigned)f2b(o[2 * k + 1]) << 16);
            *(uint4*)((unsigned short*)y + (size_t)v * 128 + p * 8) = packed;
        } else {
            float* yf = (float*)y + (size_t)v * 128 + p * 8;
            *(float4*)yf = make_float4(o[0], o[1], o[2], o[3]);
            *(float4*)(yf + 4) = make_float4(o[4], o[5], o[6], o[7]);
        }
        if (STATS) {
#pragma unroll
            for (int k = 0; k < 8; ++k) sv[grp][p * 8 + k] = o[k];
        }
    }

    if (STATS) {
        __syncthreads();   // uniform: STATS is compile-time
        if (tid < 128) {
            float s = 0.f, q = 0.f;
#pragma unroll
            for (int r = 0; r < 16; ++r) {
                float val = sv[r][tid];
                s += val;
                q += val * val;
            }
            int slot = blockIdx.x & (NSLOTS - 1);
            atomicAdd(&sumP[slot * 128 + tid], s);
            atomicAdd(&sqP[slot * 128 + tid], q);
        }
    }
}

// ---------- MFMA bf16 GEMM (64x64, LDT=40), register-prefetched K loop ----------
template <bool RELU, bool STATS>
__global__ void __launch_bounds__(256) mfma_gemm_kernel(const unsigned short* __restrict__ A,
                                                        const unsigned short* __restrict__ Bt,
                                                        const float* __restrict__ bias,
                                                        unsigned short* __restrict__ C,
                                                        float* __restrict__ sums,
                                                        float* __restrict__ sumsqs,
                                                        int M, int N, int K) {
    const int LDT = 40;  // 32 + 8 pad (ushorts)
    __shared__ unsigned short As[64 * LDT];
    __shared__ unsigned short Bs[64 * LDT];
    int tid = threadIdx.x;
    int bm = blockIdx.x * 64;
    int bn = blockIdx.y * 64;
    int lr = tid >> 2;
    int lc = (tid & 3) * 8;
    int lane = tid & 63;
    int w = tid >> 6;
    int wr = (w >> 1) * 32, wc = (w & 1) * 32;
    int l15 = lane & 15, q = lane >> 4;

    f32x4 acc[2][2] = {};
    bool arow_ok = (bm + lr) < M;
    const unsigned short* Aptr = A + (size_t)(bm + lr) * K + lc;
    const unsigned short* Bptr = Bt + (size_t)(bn + lr) * K + lc;

    uint4 av = arow_ok ? *(const uint4*)(Aptr) : make_uint4(0u, 0u, 0u, 0u);
    uint4 bv = *(const uint4*)(Bptr);

    for (int k0 = 0; k0 < K; k0 += 32) {
        *(uint4*)&As[lr * LDT + lc] = av;
        *(uint4*)&Bs[lr * LDT + lc] = bv;
        __syncthreads();
        if (k0 + 32 < K) {   // prefetch next tile; latency hides under ds_read+MFMA
            av = arow_ok ? *(const uint4*)(Aptr + k0 + 32) : make_uint4(0u, 0u, 0u, 0u);
            bv = *(const uint4*)(Bptr + k0 + 32);
        }
        bf16x8 a0 = *(const bf16x8*)&As[(wr + 0 + l15) * LDT + q * 8];
        bf16x8 a1 = *(const bf16x8*)&As[(wr + 16 + l15) * LDT + q * 8];
        bf16x8 b0 = *(const bf16x8*)&Bs[(wc + 0 + l15) * LDT + q * 8];
        bf16x8 b1 = *(const bf16x8*)&Bs[(wc + 16 + l15) * LDT + q * 8];
        acc[0][0] = __builtin_amdgcn_mfma_f32_16x16x32_bf16(a0, b0, acc[0][0], 0, 0, 0);
        acc[0][1] = __builtin_amdgcn_mfma_f32_16x16x32_bf16(a0, b1, acc[0][1], 0, 0, 0);
        acc[1][0] = __builtin_amdgcn_mfma_f32_16x16x32_bf16(a1, b0, acc[1][0], 0, 0, 0);
        acc[1][1] = __builtin_amdgcn_mfma_f32_16x16x32_bf16(a1, b1, acc[1][1], 0, 0, 0);
        __syncthreads();
    }

    float scol[2] = {0.f, 0.f};
    float qcol[2] = {0.f, 0.f};
#pragma unroll
    for (int mi = 0; mi < 2; ++mi)
#pragma unroll
        for (int ni = 0; ni < 2; ++ni) {
            int colc = bn + wc + ni * 16 + l15;
            float bv2 = bias ? bias[colc] : 0.f;
#pragma unroll
            for (int r = 0; r < 4; ++r) {
                int row = bm + wr + mi * 16 + q * 4 + r;
                if (row < M) {
                    float vv = acc[mi][ni][r] + bv2;
                    if (RELU) vv = fmaxf(vv, 0.f);
                    C[(size_t)row * N + colc] = f2b(vv);
                    if (STATS) { scol[ni] += vv; qcol[ni] += vv * vv; }
                }
            }
        }

    if (STATS) {
        __shared__ float sred[4][2][16];
        __shared__ float qred[4][2][16];
#pragma unroll
        for (int ni = 0; ni < 2; ++ni) {
            float s = scol[ni], qq = qcol[ni];
            s += __shfl_xor(s, 16, 64);
            s += __shfl_xor(s, 32, 64);
            qq += __shfl_xor(qq, 16, 64);
            qq += __shfl_xor(qq, 32, 64);
            if (lane < 16) { sred[w][ni][l15] = s; qred[w][ni][l15] = qq; }
        }
        __syncthreads();
        if (tid < 64) {
            int par = (tid >> 5) & 1;
            int ni = (tid >> 4) & 1;
            int l = tid & 15;
            int slot = blockIdx.x & (GSLOTS - 1);
            atomicAdd(&sums[slot * HID_DIM + bn + tid],
                      sred[par][ni][l] + sred[par + 2][ni][l]);
            atomicAdd(&sumsqs[slot * HID_DIM + bn + tid],
                      qred[par][ni][l] + qred[par + 2][ni][l]);
        }
    }
}

// ---------- fold BN1 into W2 (8 blocks); reduces GSLOTS stat partials first ----------
__global__ void __launch_bounds__(256) prep2_kernel(const float* __restrict__ sum1P,
                                                    const float* __restrict__ sumsq1P,
                                                    const float* __restrict__ gamma1,
                                                    const float* __restrict__ beta1,
                                                    const float* __restrict__ W2,
                                                    unsigned short* __restrict__ W2pt,
                                                    float* __restrict__ bc2) {
    __shared__ float a1s[HID_DIM], s1s[HID_DIM];
    __shared__ float bp[16][17];
    int t = threadIdx.x;
    {
        float s = 0.f, q = 0.f;
#pragma unroll 8
        for (int j = 0; j < GSLOTS; ++j) {
            s += sum1P[j * HID_DIM + t];
            q += sumsq1P[j * HID_DIM + t];
        }
        float m = s * (1.f / N_NODES);
        float var = q * (1.f / N_NODES) - m * m;
        float a = gamma1[t] * rsqrtf(var + EPS);
        a1s[t] = a;
        s1s[t] = beta1[t] - m * a;
    }
    __syncthreads();
    int row = blockIdx.x * 16 + (t & 15);
    int ks = t >> 4;
    float bacc = 0.f;
    unsigned short wloc[16];
#pragma unroll
    for (int j = 0; j < 16; ++j) {
        int k = ks * 16 + j;
        float wv = W2[k * EMB_DIM + row];
        wloc[j] = f2b(a1s[k] * wv);
        bacc += s1s[k] * wv;
    }
    *(uint4*)&W2pt[(size_t)row * HID_DIM + ks * 16]     = *(uint4*)&wloc[0];
    *(uint4*)&W2pt[(size_t)row * HID_DIM + ks * 16 + 8] = *(uint4*)&wloc[8];
    bp[t & 15][ks] = bacc;
    __syncthreads();
    if (t < 16) {
        float s = 0.f;
#pragma unroll
        for (int g = 0; g < 16; ++g) s += bp[t][g];
        bc2[blockIdx.x * 16 + t] = s;
    }
}

// ---------- segmented max per graph; finalizes layer-2 partial stats in-block ----------
__global__ void __launch_bounds__(128) segmax_kernel(const float* __restrict__ y,
                                                     const float* __restrict__ sumP,
                                                     const float* __restrict__ sqP,
                                                     const float* __restrict__ gamma2,
                                                     const float* __restrict__ beta2,
                                                     const int* __restrict__ batch,
                                                     float* __restrict__ out) {
    __shared__ int sh[2];
    int g = blockIdx.x;
    int c = threadIdx.x;
    float s2 = 0.f, q2 = 0.f;
#pragma unroll 8
    for (int j = 0; j < NSLOTS; ++j) {
        s2 += sumP[j * 128 + c];
        q2 += sqP[j * 128 + c];
    }
    float mch = s2 * (1.f / N_NODES);
    float var = q2 * (1.f / N_NODES) - mch * mch;
    float ac = gamma2[c] * rsqrtf(var + EPS);
    float sc = beta2[c] - mch * ac;
    if (threadIdx.x == 0) {
        int lo = 0, hi = N_NODES;
        while (lo < hi) { int mid = (lo + hi) >> 1; if (batch[mid] < g) lo = mid + 1; else hi = mid; }
        sh[0] = lo;
        hi = N_NODES;
        while (lo < hi) { int mid = (lo + hi) >> 1; if (batch[mid] < g + 1) lo = mid + 1; else hi = mid; }
        sh[1] = lo;
    }
    __syncthreads();
    int beg = sh[0], end = sh[1];
    float m = -INFINITY;
    for (int v = beg; v < end; ++v) {
        m = fmaxf(m, fmaf(ac, y[(size_t)v * EMB_DIM + c], sc));
    }
    out[(size_t)g * EMB_DIM + c] = m;
}

extern "C" void kernel_launch(void* const* d_in, const int* in_sizes, int n_in,
                              void* d_out, int out_size, void* d_ws, size_t ws_size,
                              hipStream_t stream) {
    const float* x      = (const float*)d_in[0];
    const int*   ei     = (const int*)d_in[1];
    const int*   batch  = (const int*)d_in[2];
    const float* W1     = (const float*)d_in[3];
    const float* b1     = (const float*)d_in[4];
    const float* gamma1 = (const float*)d_in[5];
    const float* beta1  = (const float*)d_in[6];
    const float* W2     = (const float*)d_in[7];
    const float* b2     = (const float*)d_in[8];
    const float* gamma2 = (const float*)d_in[9];
    const float* beta2  = (const float*)d_in[10];
    float* out = (float*)d_out;

    char* ws = (char*)d_ws;
    size_t off = 0;
    auto alloc = [&](size_t bytes) -> char* {
        char* p = ws + off;
        off = (off + bytes + 255) & ~(size_t)255;
        return p;
    };
    int*   gcur    = (int*)alloc((size_t)NB * 4);                  // bucket cursors
    float* gsumP   = (float*)alloc((size_t)GSLOTS * HID_DIM * 4);  // layer-1 stat partials
    float* gsqP    = (float*)alloc((size_t)GSLOTS * HID_DIM * 4);
    float* sumP    = (float*)alloc((size_t)NSLOTS * 128 * 4);      // layer-2 stat partials
    float* sqP     = (float*)alloc((size_t)NSLOTS * 128 * 4);
    size_t zbytes = off;
    int*   fill   = (int*)alloc((size_t)N_NODES * 4);              // fully overwritten by build_ell
    int*   bucketbuf = (int*)alloc((size_t)NB * CAP * 4);
    int*   col    = (int*)alloc((size_t)N_NODES * ELLW * 4);
    float* bc2    = (float*)alloc((size_t)EMB_DIM * 4);
    unsigned short* W1t  = (unsigned short*)alloc((size_t)HID_DIM * IN_DIM * 2);
    unsigned short* W2pt = (unsigned short*)alloc((size_t)HID_DIM * EMB_DIM * 2);
    unsigned short* xbf  = (unsigned short*)alloc((size_t)N_NODES * IN_DIM * 2);   // also y2 region
    unsigned short* axbf = (unsigned short*)alloc((size_t)N_NODES * IN_DIM * 2);
    unsigned short* y1bf = (unsigned short*)alloc((size_t)N_NODES * HID_DIM * 2);
    unsigned short* gbf  = (unsigned short*)alloc((size_t)N_NODES * EMB_DIM * 2);
    float* y2 = (float*)xbf;  // xbf+axbf dead by layer 2; contiguous 25.6 MB
    (void)ws_size; (void)in_sizes; (void)n_in; (void)out_size;

    const int* src  = ei;
    const int* dstp = ei + N_EDGES;

    hipMemsetAsync(ws, 0, zbytes, stream);   // zero gcur + all stat partials in one call

    // merged: phase-A bucketing (single scan) + x->bf16 + W1 transpose
    scatter_convert<<<PA_BLOCKS + F2B_BLOCKS + TW1_BLOCKS, 256, 0, stream>>>(
        src, dstp, gcur, bucketbuf, x, xbf, W1, W1t);
    // phase B: per-bucket ELL build via LDS atomics, coalesced flush
    build_ell<<<NB, 256, 0, stream>>>(gcur, bucketbuf, fill, col);

    // Layer 1: ax = A x (bf16), y1 = relu(ax@W1 + b1) (bf16) with slotted column stats
    aggw_kernel<false, true, false, false><<<N_NODES / 16, 256, 0, stream>>>(
        xbf, fill, col, nullptr, axbf, nullptr, nullptr);
    dim3 g1((N_NODES + 63) / 64, HID_DIM / 64);
    mfma_gemm_kernel<true, true><<<g1, 256, 0, stream>>>(axbf, W1t, b1, y1bf,
                                                         gsumP, gsqP,
                                                         N_NODES, HID_DIM, IN_DIM);

    // Fold BN1 into W2 (transposed bf16) + pre-aggregation column bias bc2
    prep2_kernel<<<8, 256, 0, stream>>>(gsumP, gsqP, gamma1, beta1, W2, W2pt, bc2);

    // Layer 2: g = y1@W2p + bc2 (bf16), y2 = relu(A g + b2) (fp32) with slotted stats
    dim3 g2((N_NODES + 63) / 64, EMB_DIM / 64);
    mfma_gemm_kernel<false, false><<<g2, 256, 0, stream>>>(y1bf, W2pt, bc2, gbf,
                                                           nullptr, nullptr,
                                                           N_NODES, EMB_DIM, HID_DIM);
    aggw_kernel<true, false, true, true><<<N_NODES / 16, 256, 0, stream>>>(
        gbf, fill, col, b2, y2, sumP, sqP);

    // fused BN2-finalize (reduce NSLOTS partials) + per-graph segmented max
    segmax_kernel<<<N_GRAPHS, 128, 0, stream>>>(y2, sumP, sqP,
                                                gamma2, beta2, batch, out);
}